// Round 3
// baseline (553.216 us; speedup 1.0000x reference)
//
#include <hip/hip_runtime.h>
#include <hip/hip_fp16.h>

typedef __attribute__((ext_vector_type(8))) short short8;
typedef __attribute__((ext_vector_type(4))) float f32x4;

#define TT 2048
#define DD 512

__device__ __forceinline__ unsigned short f2bf(float f) {
  unsigned int u = __float_as_uint(f);
  u += 0x7FFFu + ((u >> 16) & 1u);
  return (unsigned short)(u >> 16);
}
__device__ __forceinline__ unsigned short f2h(float f) {
  return __half_as_ushort(__float2half(f));
}
__device__ __forceinline__ float h2f(unsigned short u) {
  return __half2float(__ushort_as_half(u));
}
__device__ __forceinline__ void gload16(const void* g, void* l) {
  __builtin_amdgcn_global_load_lds((const __attribute__((address_space(1))) void*)g,
                                   (__attribute__((address_space(3))) void*)l, 16, 0, 0);
}

// ---------- prep kernels ----------

__global__ void xconv_kernel(const float* __restrict__ x, unsigned short* __restrict__ xbf) {
  int i = blockIdx.x * 256 + threadIdx.x;
  const float4* p = (const float4*)x + (size_t)i * 2;
  float4 a = p[0], b = p[1];
  short8 o;
  o[0] = f2bf(a.x); o[1] = f2bf(a.y); o[2] = f2bf(a.z); o[3] = f2bf(a.w);
  o[4] = f2bf(b.x); o[5] = f2bf(b.y); o[6] = f2bf(b.z); o[7] = f2bf(b.w);
  *((short8*)xbf + i) = o;
}

__global__ void wtrans_kernel(const float* __restrict__ Wf,
                              const float* __restrict__ Wb,
                              unsigned short* __restrict__ wt) {
  __shared__ float tile[32][33];
  int bid = blockIdx.x;            // 2 * 16 * 48
  int d   = bid / 768;
  int rem = bid - d * 768;
  int kt = rem & 15;
  int ct = rem >> 4;
  const float* W = d ? Wb : Wf;
  int k0 = kt * 32, c0 = ct * 32;
  int r = threadIdx.x >> 5, c = threadIdx.x & 31;
#pragma unroll
  for (int i = 0; i < 4; i++)
    tile[r + 8*i][c] = W[(size_t)(k0 + r + 8*i) * 1536 + c0 + c];
  __syncthreads();
  unsigned short* outp = wt + ((size_t)d * 1536 + c0) * 512 + k0;
#pragma unroll
  for (int i = 0; i < 4; i++)
    outp[(size_t)(r + 8*i) * 512 + c] = f2bf(tile[c][r + 8*i]);
}

__global__ void cbias_kernel(const float* __restrict__ bf_, const float* __restrict__ bb_,
                             float* __restrict__ cb) {
  int n = blockIdx.x * 256 + threadIdx.x;   // 3072
  cb[n] = (n < 1536) ? bf_[n] : bb_[n - 1536];
}

// ---------- GEMM + activation: 256x256 tile, BK=64, 4-slot LDS ring, counted vmcnt ----------
// Slots (16KB each): A-k0 @0, A-k1 @16384, B-k0 @32768, B-k1 @49152. 64KB total.
// Per phase: ds_read frags | stage 1 half (2 gload_lds) | barrier | lgkmcnt(0) | 16 MFMA.
// vmcnt(2) at phases 0,2 only -> loads never drain to 0.
__global__ __launch_bounds__(512, 2)
void gemm8_kernel(const unsigned short* __restrict__ xbf,
                  const unsigned short* __restrict__ wt,
                  const float* __restrict__ cbias,
                  unsigned short* __restrict__ G,
                  int ncbn, int gstride) {
  __shared__ __align__(16) char smem[65536];

  int bid = blockIdx.x;
  int cpx = gridDim.x >> 3;
  int bid2 = (bid & 7) * cpx + (bid >> 3);
  int bm = bid2 / ncbn, bn = bid2 - bm * ncbn;
  size_t m0 = (size_t)bm * 256;
  int n0 = bn * 256;

  int tid = threadIdx.x, lane = tid & 63, wv = tid >> 6;
  int wm = wv >> 2, wn = wv & 3;          // 2 x 4 wave grid; per-wave 128 x 64

  // fragment LDS offsets within a slot: [256 rows][64B rows], swz block = (row>>1)&3
  int aoff[8], boff[4];
#pragma unroll
  for (int m = 0; m < 8; ++m) {
    int row = wm * 128 + m * 16 + (lane & 15);
    aoff[m] = row * 64 + ((((lane >> 4) << 4)) ^ ((((row >> 1) & 3)) << 4));
  }
#pragma unroll
  for (int n = 0; n < 4; ++n) {
    int row = wn * 64 + n * 16 + (lane & 15);
    boff[n] = row * 64 + ((((lane >> 4) << 4)) ^ ((((row >> 1) & 3)) << 4));
  }

  // staging: thread covers rows tid>>2 and +128, kbyte (tid&3)*16, inverse-swizzled source
  int srow = tid >> 2;
  int skb = (tid & 3) * 16;
  int c0 = skb ^ (((srow >> 1) & 3) << 4);
  const char* aSrc = (const char*)xbf + (m0 + srow) * 1024 + c0;
  const char* bSrc = (const char*)wt + (size_t)(n0 + srow) * 1024 + c0;

  f32x4 acc[8][4];
#pragma unroll
  for (int m = 0; m < 8; ++m)
#pragma unroll
    for (int n = 0; n < 4; ++n)
      acc[m][n] = f32x4{0.f, 0.f, 0.f, 0.f};

  short8 areg[8];

  // prologue: A0(0), B0(0), A1(0)  (6 loads)
  gload16(aSrc, smem + tid * 16);
  gload16(aSrc + 131072, smem + 8192 + tid * 16);
  gload16(bSrc, smem + 32768 + tid * 16);
  gload16(bSrc + 131072, smem + 32768 + 8192 + tid * 16);
  gload16(aSrc + 64, smem + 16384 + tid * 16);
  gload16(aSrc + 131072 + 64, smem + 16384 + 8192 + tid * 16);

#define PHASE(KK, NN, SSLOT, SSRC, SKB, DOVM)                                  \
  {                                                                            \
    if (DOVM) asm volatile("s_waitcnt vmcnt(2)" ::: "memory");                 \
    __builtin_amdgcn_s_barrier();                                              \
    if ((NN) == 0) {                                                           \
      _Pragma("unroll")                                                        \
      for (int m = 0; m < 8; ++m)                                              \
        areg[m] = *(const short8*)(smem + (KK) * 16384 + aoff[m]);             \
    }                                                                          \
    short8 b0 = *(const short8*)(smem + 32768 + (KK) * 16384 + boff[2 * (NN)]);     \
    short8 b1 = *(const short8*)(smem + 32768 + (KK) * 16384 + boff[2 * (NN) + 1]); \
    gload16((SSRC) + (SKB), smem + (SSLOT) + tid * 16);                        \
    gload16((SSRC) + 131072 + (SKB), smem + (SSLOT) + 8192 + tid * 16);        \
    asm volatile("s_waitcnt lgkmcnt(0)" ::: "memory");                         \
    __builtin_amdgcn_sched_barrier(0);                                         \
    __builtin_amdgcn_s_setprio(1);                                             \
    _Pragma("unroll")                                                          \
    for (int m = 0; m < 8; ++m) {                                              \
      acc[m][2 * (NN)] = __builtin_amdgcn_mfma_f32_16x16x32_bf16(              \
          areg[m], b0, acc[m][2 * (NN)], 0, 0, 0);                             \
      acc[m][2 * (NN) + 1] = __builtin_amdgcn_mfma_f32_16x16x32_bf16(          \
          areg[m], b1, acc[m][2 * (NN) + 1], 0, 0, 0);                         \
    }                                                                          \
    __builtin_amdgcn_s_setprio(0);                                             \
  }

  for (int kt = 0; kt < 8; ++kt) {
    int kb = kt * 128;
    PHASE(0, 0, 49152, bSrc, kb + 64, 1)   // stage B1(kt)
    PHASE(0, 1, 0,     aSrc, kb + 128, 0)  // stage A0(kt+1)
    PHASE(1, 0, 32768, bSrc, kb + 128, 1)  // stage B0(kt+1)
    PHASE(1, 1, 16384, aSrc, kb + 192, 0)  // stage A1(kt+1)
  }
#undef PHASE

  asm volatile("s_waitcnt vmcnt(0)" ::: "memory");
  __builtin_amdgcn_s_barrier();

  // epilogue: bias + act -> fp16 -> per-wave LDS transpose (2 rounds of 64 rows) -> store
  float cbv[4];
#pragma unroll
  for (int n = 0; n < 4; ++n)
    cbv[n] = cbias[n0 + wn * 64 + n * 16 + (lane & 15)];
  int g3 = (n0 % 1536) >> 9;   // 0 = z (tanh), else sigmoid
  char* wbase = smem + wv * 8192;

#pragma unroll
  for (int rr = 0; rr < 2; ++rr) {
#pragma unroll
    for (int m4 = 0; m4 < 4; ++m4) {
      int m = rr * 4 + m4;
#pragma unroll
      for (int n = 0; n < 4; ++n) {
        int col2 = (n * 16 + (lane & 15)) * 2;
#pragma unroll
        for (int r = 0; r < 4; ++r) {
          int rowl = m4 * 16 + (lane >> 4) * 4 + r;
          float v = acc[m][n][r] + cbv[n];
          float a;
          if (g3 == 0) { float e = __expf(2.f * v); a = 1.f - 2.f / (e + 1.f); }
          else         { a = 1.f / (1.f + __expf(-v)); }
          *(unsigned short*)(wbase + rowl * 128 + (col2 ^ ((rowl & 7) << 4))) = f2h(a);
        }
      }
    }
    asm volatile("s_waitcnt lgkmcnt(0)" ::: "memory");
    __builtin_amdgcn_sched_barrier(0);
#pragma unroll
    for (int pass = 0; pass < 8; ++pass) {
      int rowl = pass * 8 + (lane >> 3);
      int blk = ((lane & 7) ^ (rowl & 7)) * 16;
      short8 vv = *(const short8*)(wbase + rowl * 128 + blk);
      size_t grow = m0 + wm * 128 + rr * 64 + rowl;
      int gcol = n0 + wn * 64 + (lane & 7) * 8;
      *(short8*)((char*)G + (grow * gstride + gcol) * 2) = vv;
    }
  }
}

// ---------- chunked scan (pair-vectorized) ----------

__global__ void scan_carry_kernel(const unsigned short* __restrict__ G,
                                  float2* __restrict__ carry, int gstride, int C) {
  int C2 = C >> 9;
  int bid = blockIdx.x;
  int b = bid / (16 * C2); int rem = bid - b * (16 * C2);
  int ch = rem / C2; int grp = rem - ch * C2;
  int q0 = grp * 512 + threadIdx.x * 2;
  int dir = q0 >> 9, h = q0 & 511;
  size_t row0 = (size_t)b * TT + ch * 128;
  const unsigned short* p = G + row0 * gstride + dir * 1536 + h;
  float A0 = 1.f, B0 = 0.f, A1 = 1.f, B1 = 0.f;
#pragma unroll 4
  for (int t = 0; t < 128; ++t) {
    unsigned int zz = *(const unsigned int*)(p);
    unsigned int ff = *(const unsigned int*)(p + 512);
    float z0 = h2f((unsigned short)zz), z1 = h2f((unsigned short)(zz >> 16));
    float f0 = h2f((unsigned short)ff), f1 = h2f((unsigned short)(ff >> 16));
    B0 = f0 * B0 + (1.f - f0) * z0; A0 *= f0;
    B1 = f1 * B1 + (1.f - f1) * z1; A1 *= f1;
    p += gstride;
  }
  float4 st = {A0, B0, A1, B1};
  *(float4*)&carry[(size_t)(b * 16 + ch) * C + q0] = st;
}

__global__ void scan_combine_kernel(const float2* __restrict__ carry,
                                    float* __restrict__ cin, int C) {
  int gid = blockIdx.x * 256 + threadIdx.x;  // 32*C
  int b = gid / C, q = gid - b * C;
  float c = 0.f;
#pragma unroll
  for (int ch = 0; ch < 16; ++ch) {
    size_t idx = (size_t)(b * 16 + ch) * C + q;
    cin[idx] = c;
    float2 ab = carry[idx];
    c = ab.x * c + ab.y;
  }
}

__global__ void scan_final_kernel(const unsigned short* __restrict__ G,
                                  const float* __restrict__ cin,
                                  float* __restrict__ out,
                                  int gstride, int C, int dbase) {
  int C2 = C >> 9;
  int bid = blockIdx.x;
  int b = bid / (16 * C2); int rem = bid - b * (16 * C2);
  int ch = rem / C2; int grp = rem - ch * C2;
  int q0 = grp * 512 + threadIdx.x * 2;
  int dir = q0 >> 9, h = q0 & 511;
  size_t row0 = (size_t)b * TT + ch * 128;
  const unsigned short* p = G + row0 * gstride + dir * 1536 + h;
  float* po = out + row0 * 1024 + (size_t)(dbase + dir) * 512 + h;
  float2 cc = *(const float2*)&cin[(size_t)(b * 16 + ch) * C + q0];
  float c0 = cc.x, c1 = cc.y;
#pragma unroll 4
  for (int t = 0; t < 128; ++t) {
    unsigned int zz = *(const unsigned int*)(p);
    unsigned int ff = *(const unsigned int*)(p + 512);
    unsigned int oo = *(const unsigned int*)(p + 1024);
    float z0 = h2f((unsigned short)zz), z1 = h2f((unsigned short)(zz >> 16));
    float f0 = h2f((unsigned short)ff), f1 = h2f((unsigned short)(ff >> 16));
    float o0 = h2f((unsigned short)oo), o1 = h2f((unsigned short)(oo >> 16));
    c0 = f0 * c0 + (1.f - f0) * z0;
    c1 = f1 * c1 + (1.f - f1) * z1;
    float2 ov = {o0 * c0, o1 * c1};
    *(float2*)po = ov;
    p += gstride; po += 1024;
  }
}

// ---------- round-1 fused fallback (small-ws path) ----------
#define NB 192
#define BT 64
__global__ __launch_bounds__(256, 2)
void qrnn_kernel(const float* __restrict__ x,
                 const float* __restrict__ bf_, const float* __restrict__ bb_,
                 const unsigned short* __restrict__ wt,
                 float* __restrict__ out) {
  __shared__ __align__(16) unsigned short sA[64 * 64];
  __shared__ float sG[64 * 193];
  __shared__ float sBias[NB];
  const int tid  = threadIdx.x;
  const int lane = tid & 63;
  const int wv   = tid >> 6;
  int p = blockIdx.x;
  int xcd = p & 7, slot = p >> 3;
  int b   = xcd * 4 + (slot >> 4);
  int v   = slot & 15;
  int dir = v >> 3, ht = v & 7;
  int h0  = ht * 64;
  if (tid < NB) {
    const float* bsrc = dir ? bb_ : bf_;
    sBias[tid] = bsrc[((tid >> 6) << 9) + h0 + (tid & 63)];
  }
  const float* xb = x + (size_t)b * TT * DD;
  const unsigned short* wtd = wt + (size_t)dir * 1536 * 512;
  size_t brow[3];
#pragma unroll
  for (int j = 0; j < 3; j++) {
    int n = 48 * wv + 16 * j + (lane & 15);
    brow[j] = (size_t)(((n >> 6) << 9) + h0 + (n & 63)) * 512 + 8 * (lane >> 4);
  }
  int a_off[2][4];
#pragma unroll
  for (int kk = 0; kk < 2; kk++)
#pragma unroll
    for (int m = 0; m < 4; m++) {
      int row = 16 * m + (lane & 15);
      a_off[kk][m] = row * 128 + ((64 * kk + 16 * (lane >> 4)) ^ ((row & 7) << 4));
    }
  int s_trow[4], s_kq[4], s_woff[4];
#pragma unroll
  for (int i = 0; i < 4; i++) {
    int q = tid + 256 * i;
    s_trow[i] = q >> 4;
    s_kq[i]   = q & 15;
    s_woff[i] = s_trow[i] * 128 + ((8 * s_kq[i]) ^ ((s_trow[i] & 7) << 4));
  }
  float c = 0.f;
  f32x4 acc[4][3];
  for (int t0 = 0; t0 < TT; t0 += BT) {
#pragma unroll
    for (int m = 0; m < 4; m++)
#pragma unroll
      for (int j = 0; j < 3; j++)
        acc[m][j] = f32x4{0.f, 0.f, 0.f, 0.f};
    float4 vv[4];
#pragma unroll
    for (int i = 0; i < 4; i++)
      vv[i] = *(const float4*)(xb + (size_t)(t0 + s_trow[i]) * DD + 4 * s_kq[i]);
#pragma unroll
    for (int ks = 0; ks < 8; ks++) {
      __syncthreads();
#pragma unroll
      for (int i = 0; i < 4; i++) {
        ushort4 u;
        u.x = f2bf(vv[i].x); u.y = f2bf(vv[i].y);
        u.z = f2bf(vv[i].z); u.w = f2bf(vv[i].w);
        *(ushort4*)((char*)sA + s_woff[i]) = u;
      }
      if (ks < 7) {
        int k0n = (ks + 1) * 64;
#pragma unroll
        for (int i = 0; i < 4; i++)
          vv[i] = *(const float4*)(xb + (size_t)(t0 + s_trow[i]) * DD + k0n + 4 * s_kq[i]);
      }
      __syncthreads();
      const char* sAb = (const char*)sA;
      int k0 = ks * 64;
#pragma unroll
      for (int kk = 0; kk < 2; kk++) {
        short8 bfr[3];
#pragma unroll
        for (int j = 0; j < 3; j++)
          bfr[j] = *(const short8*)(wtd + brow[j] + k0 + 32 * kk);
#pragma unroll
        for (int m = 0; m < 4; m++) {
          short8 afr = *(const short8*)(sAb + a_off[kk][m]);
#pragma unroll
          for (int j = 0; j < 3; j++)
            acc[m][j] = __builtin_amdgcn_mfma_f32_16x16x32_bf16(afr, bfr[j], acc[m][j], 0, 0, 0);
        }
      }
    }
#pragma unroll
    for (int m = 0; m < 4; m++)
#pragma unroll
      for (int j = 0; j < 3; j++) {
        int col   = 48 * wv + 16 * j + (lane & 15);
        int rbase = 16 * m + 4 * (lane >> 4);
#pragma unroll
        for (int r = 0; r < 4; r++)
          sG[(rbase + r) * 193 + col] = acc[m][j][r];
      }
    __syncthreads();
    for (int idx = tid; idx < 64 * NB; idx += 256) {
      int t = idx / NB;
      int n = idx - t * NB;
      float g = sG[t * 193 + n] + sBias[n];
      float res;
      if (n < 64) { float e = __expf(2.f * g); res = 1.f - 2.f / (e + 1.f); }
      else        { res = 1.f / (1.f + __expf(-g)); }
      sG[t * 193 + n] = res;
    }
    __syncthreads();
    if (tid < 64) {
      float* og = out + ((size_t)(b * TT + t0)) * 1024 + (dir << 9) + h0 + tid;
      float cc = c;
#pragma unroll 8
      for (int t = 0; t < BT; t++) {
        float z = sG[t * 193 + tid];
        float f = sG[t * 193 + 64 + tid];
        float o = sG[t * 193 + 128 + tid];
        cc = z + f * (cc - z);
        og[(size_t)t << 10] = o * cc;
      }
      c = cc;
    }
  }
}

extern "C" void kernel_launch(void* const* d_in, const int* in_sizes, int n_in,
                              void* d_out, int out_size, void* d_ws, size_t ws_size,
                              hipStream_t stream) {
  const float* x   = (const float*)d_in[0];
  const float* W_f = (const float*)d_in[1];
  const float* b_f = (const float*)d_in[2];
  const float* W_b = (const float*)d_in[3];
  const float* b_b = (const float*)d_in[4];
  float* out = (float*)d_out;

  char* ws = (char*)d_ws;
  const size_t OFF_WT    = 0;                    // 3,145,728
  const size_t OFF_CB    = 3145728;              // 12,288
  const size_t OFF_CARRY = 3158016;              // 4 MiB
  const size_t OFF_CIN   = 7352320;              // 2 MiB
  const size_t OFF_XBF   = 9449472;              // 64 MiB
  const size_t OFF_G     = 76558336;
  const size_t NEED_FULL = OFF_G + 402653184ull; // 479.2 MB
  const size_t NEED_DIR  = OFF_G + 201326592ull; // 277.9 MB

  unsigned short* wt   = (unsigned short*)(ws + OFF_WT);
  float* cbias         = (float*)(ws + OFF_CB);
  float2* carry        = (float2*)(ws + OFF_CARRY);
  float* cin           = (float*)(ws + OFF_CIN);
  unsigned short* xbf  = (unsigned short*)(ws + OFF_XBF);
  unsigned short* G    = (unsigned short*)(ws + OFF_G);

  if (ws_size >= NEED_FULL) {
    xconv_kernel<<<16384, 256, 0, stream>>>(x, xbf);
    wtrans_kernel<<<1536, 256, 0, stream>>>(W_f, W_b, wt);
    cbias_kernel<<<12, 256, 0, stream>>>(b_f, b_b, cbias);
    gemm8_kernel<<<3072, 512, 0, stream>>>(xbf, wt, cbias, G, 12, 3072);
    scan_carry_kernel<<<1024, 256, 0, stream>>>(G, carry, 3072, 1024);
    scan_combine_kernel<<<128, 256, 0, stream>>>(carry, cin, 1024);
    scan_final_kernel<<<1024, 256, 0, stream>>>(G, cin, out, 3072, 1024, 0);
  } else if (ws_size >= NEED_DIR) {
    xconv_kernel<<<16384, 256, 0, stream>>>(x, xbf);
    wtrans_kernel<<<1536, 256, 0, stream>>>(W_f, W_b, wt);
    cbias_kernel<<<12, 256, 0, stream>>>(b_f, b_b, cbias);
    for (int dir = 0; dir < 2; ++dir) {
      gemm8_kernel<<<1536, 512, 0, stream>>>(xbf, wt + (size_t)dir * 1536 * 512,
                                             cbias + dir * 1536, G, 6, 1536);
      scan_carry_kernel<<<512, 256, 0, stream>>>(G, carry, 1536, 512);
      scan_combine_kernel<<<64, 256, 0, stream>>>(carry, cin, 512);
      scan_final_kernel<<<512, 256, 0, stream>>>(G, cin, out, 1536, 512, dir);
    }
  } else {
    wtrans_kernel<<<1536, 256, 0, stream>>>(W_f, W_b, wt);
    qrnn_kernel<<<512, 256, 0, stream>>>(x, b_f, b_b, wt, out);
  }
}

// Round 4
// 544.020 us; speedup vs baseline: 1.0169x; 1.0169x over previous
//
#include <hip/hip_runtime.h>
#include <hip/hip_fp16.h>

typedef __attribute__((ext_vector_type(8))) short short8;
typedef __attribute__((ext_vector_type(4))) float f32x4;

#define TT 2048
#define DD 512

__device__ __forceinline__ unsigned short f2bf(float f) {
  unsigned int u = __float_as_uint(f);
  u += 0x7FFFu + ((u >> 16) & 1u);
  return (unsigned short)(u >> 16);
}
__device__ __forceinline__ unsigned short f2h(float f) {
  return __half_as_ushort(__float2half(f));
}
__device__ __forceinline__ float h2f(unsigned short u) {
  return __half2float(__ushort_as_half(u));
}
__device__ __forceinline__ unsigned int packh2(float a, float b) {
  return (unsigned int)f2h(a) | ((unsigned int)f2h(b) << 16);
}
__device__ __forceinline__ void gload16(const void* g, void* l) {
  __builtin_amdgcn_global_load_lds((const __attribute__((address_space(1))) void*)g,
                                   (__attribute__((address_space(3))) void*)l, 16, 0, 0);
}

// ---------- prep kernels ----------

__global__ void xconv_kernel(const float* __restrict__ x, unsigned short* __restrict__ xbf) {
  int i = blockIdx.x * 256 + threadIdx.x;
  const float4* p = (const float4*)x + (size_t)i * 2;
  float4 a = p[0], b = p[1];
  short8 o;
  o[0] = f2bf(a.x); o[1] = f2bf(a.y); o[2] = f2bf(a.z); o[3] = f2bf(a.w);
  o[4] = f2bf(b.x); o[5] = f2bf(b.y); o[6] = f2bf(b.z); o[7] = f2bf(b.w);
  *((short8*)xbf + i) = o;
}

// W[512][1536] fp32 -> Wt[dir][n_new][512 k] bf16, n_new = (h>>7)*384 + gate*128 + (h&127)
__global__ void wtrans_new_kernel(const float* __restrict__ Wf,
                                  const float* __restrict__ Wb,
                                  unsigned short* __restrict__ wt) {
  __shared__ float tile[32][33];
  int bid = blockIdx.x;            // 2 * 16 * 48
  int d   = bid / 768;
  int rem = bid - d * 768;
  int kt = rem & 15;
  int ct = rem >> 4;
  const float* W = d ? Wb : Wf;
  int k0 = kt * 32, c0 = ct * 32;
  int r = threadIdx.x >> 5, c = threadIdx.x & 31;
#pragma unroll
  for (int i = 0; i < 4; i++)
    tile[r + 8*i][c] = W[(size_t)(k0 + r + 8*i) * 1536 + c0 + c];
  __syncthreads();
#pragma unroll
  for (int i = 0; i < 4; i++) {
    int col = c0 + r + 8*i;
    int gate = col >> 9, hh = col & 511;
    int nn = (hh >> 7) * 384 + gate * 128 + (hh & 127);
    wt[((size_t)d * 1536 + nn) * 512 + k0 + c] = f2bf(tile[c][r + 8*i]);
  }
}

// old layout for fallback kernel
__global__ void wtrans_old_kernel(const float* __restrict__ Wf,
                                  const float* __restrict__ Wb,
                                  unsigned short* __restrict__ wt) {
  __shared__ float tile[32][33];
  int bid = blockIdx.x;
  int d   = bid / 768;
  int rem = bid - d * 768;
  int kt = rem & 15;
  int ct = rem >> 4;
  const float* W = d ? Wb : Wf;
  int k0 = kt * 32, c0 = ct * 32;
  int r = threadIdx.x >> 5, c = threadIdx.x & 31;
#pragma unroll
  for (int i = 0; i < 4; i++)
    tile[r + 8*i][c] = W[(size_t)(k0 + r + 8*i) * 1536 + c0 + c];
  __syncthreads();
  unsigned short* outp = wt + ((size_t)d * 1536 + c0) * 512 + k0;
#pragma unroll
  for (int i = 0; i < 4; i++)
    outp[(size_t)(r + 8*i) * 512 + c] = f2bf(tile[c][r + 8*i]);
}

__global__ void cbias_kernel(const float* __restrict__ bf_, const float* __restrict__ bb_,
                             float* __restrict__ cb) {
  int t = blockIdx.x * 256 + threadIdx.x;   // 3072
  int d = t / 1536, cc = t - d * 1536;
  int gate = cc >> 9, hh = cc & 511;
  int nn = (hh >> 7) * 384 + gate * 128 + (hh & 127);
  cb[d * 1536 + nn] = (d ? bb_ : bf_)[cc];
}

// ---------- fused GEMM + activation + in-block fo-pool scan ----------
// Tile 128(t) x 384(3 gates x 128 h), BK=32, 16 K-iters, 4-buffer 32KB ring (128KB),
// prefetch 3 K-tiles ahead, counted vmcnt(8), 1 barrier/iter.
// Epilogue: act -> fp16 gates in LDS -> 2-level scan over 128 t -> store (p,q) u32 + carry.
__global__ __launch_bounds__(512, 2)
void gemm_scan_kernel(const unsigned short* __restrict__ xbf,
                      const unsigned short* __restrict__ wtd,
                      const float* __restrict__ cb,
                      unsigned int* __restrict__ pq,
                      float2* __restrict__ carry,
                      int nbn, int pqC, int C) {
  __shared__ __align__(16) char smem[131072];

  int bid = blockIdx.x;
  int cpx = gridDim.x >> 3;
  int bid2 = (bid & 7) * cpx + (bid >> 3);
  int bm = bid2 / nbn, bn = bid2 - bm * nbn;
  size_t m0 = (size_t)bm * 128;
  int n0 = bn * 384;
  int chbase = bn * 128;

  int tid = threadIdx.x, lane = tid & 63, wv = tid >> 6;
  int wm = wv >> 2, wn = wv & 3;     // 2 (rows) x 4 (col-frag interleave)

  // staging sources (linear LDS dest, inverse-swizzled source)
  int srow = tid >> 2;
  int sswz = ((tid & 3) * 16) ^ ((srow & 3) << 4);
  const char* aSrc = (const char*)xbf + (m0 + srow) * 1024 + sswz;
  const char* bSrc = (const char*)wtd + (size_t)(n0 + srow) * 1024 + sswz;

  // fragment LDS offsets within a 32KB buffer: A [128][64B] @0, B [384][64B] @8192
  int aoff[4], boff[6];
#pragma unroll
  for (int m = 0; m < 4; ++m) {
    int row = wm * 64 + m * 16 + (lane & 15);
    aoff[m] = row * 64 + ((((lane >> 4) * 16)) ^ ((row & 3) << 4));
  }
#pragma unroll
  for (int j = 0; j < 6; ++j) {
    int row = (wn + 4 * j) * 16 + (lane & 15);
    boff[j] = 8192 + row * 64 + ((((lane >> 4) * 16)) ^ ((row & 3) << 4));
  }

  f32x4 acc[4][6];
#pragma unroll
  for (int m = 0; m < 4; ++m)
#pragma unroll
    for (int j = 0; j < 6; ++j)
      acc[m][j] = f32x4{0.f, 0.f, 0.f, 0.f};

#define STAGE(J)                                                              \
  {                                                                           \
    char* dst = smem + ((J) & 3) * 32768;                                     \
    int kb = (J) * 64;                                                        \
    gload16(aSrc + kb, dst + tid * 16);                                       \
    gload16(bSrc + kb, dst + 8192 + tid * 16);                                \
    gload16(bSrc + 131072 + kb, dst + 16384 + tid * 16);                      \
    gload16(bSrc + 262144 + kb, dst + 24576 + tid * 16);                      \
  }

  STAGE(0) STAGE(1) STAGE(2)

#pragma unroll
  for (int j = 0; j < 16; ++j) {
    __builtin_amdgcn_s_barrier();
    if (j < 13) STAGE(j + 3)
    if (j <= 12)      asm volatile("s_waitcnt vmcnt(8)" ::: "memory");
    else if (j == 13) asm volatile("s_waitcnt vmcnt(4)" ::: "memory");
    else if (j == 14) asm volatile("s_waitcnt vmcnt(0)" ::: "memory");
    const char* base = smem + (j & 3) * 32768;
    short8 av[4], bv[6];
#pragma unroll
    for (int m = 0; m < 4; ++m) av[m] = *(const short8*)(base + aoff[m]);
#pragma unroll
    for (int jj = 0; jj < 6; ++jj) bv[jj] = *(const short8*)(base + boff[jj]);
    asm volatile("s_waitcnt lgkmcnt(0)" ::: "memory");
    __builtin_amdgcn_sched_barrier(0);
    __builtin_amdgcn_s_setprio(1);
#pragma unroll
    for (int m = 0; m < 4; ++m)
#pragma unroll
      for (int jj = 0; jj < 6; ++jj)
        acc[m][jj] = __builtin_amdgcn_mfma_f32_16x16x32_bf16(av[m], bv[jj], acc[m][jj], 0, 0, 0);
    __builtin_amdgcn_s_setprio(0);
  }
#undef STAGE

  // bias
  float cbv[6];
#pragma unroll
  for (int jj = 0; jj < 6; ++jj)
    cbv[jj] = cb[n0 + (wn + 4 * jj) * 16 + (lane & 15)];

  __syncthreads();   // all waves done with ring buffers

  // gates -> LDS fp16: z @0, f @32768, o @65536; [h][t] pairs, swizzled
#pragma unroll
  for (int m = 0; m < 4; ++m)
#pragma unroll
    for (int jj = 0; jj < 6; ++jj) {
      int fragid = wn + 4 * jj;
      int gate = fragid >> 3;
      int hh = (fragid & 7) * 16 + (lane & 15);
      int trow = wm * 64 + m * 16 + (lane >> 4) * 4;
      float v[4], a[4];
#pragma unroll
      for (int r = 0; r < 4; ++r) v[r] = acc[m][jj][r] + cbv[jj];
      if (gate == 0) {
#pragma unroll
        for (int r = 0; r < 4; ++r) { float e = __expf(2.f * v[r]); a[r] = 1.f - 2.f / (e + 1.f); }
      } else {
#pragma unroll
        for (int r = 0; r < 4; ++r) a[r] = 1.f / (1.f + __expf(-v[r]));
      }
      char* gb = smem + gate * 32768 + hh * 256;
      int sw = (hh & 15) << 4;
      *(unsigned int*)(gb + ((2 * trow) ^ sw)) = packh2(a[0], a[1]);
      *(unsigned int*)(gb + ((2 * (trow + 2)) ^ sw)) = packh2(a[2], a[3]);
    }

  __syncthreads();

  // two-level scan: thread (h = tid&127, sub = tid>>7) owns t in [sub*32, sub*32+32)
  int h = tid & 127, sub = tid >> 7;
  const char* zB = smem + h * 256;
  const char* fB = smem + 32768 + h * 256;
  const char* oB = smem + 65536 + h * 256;
  int sw = (h & 15) << 4;
  int t0 = sub * 32;

  float aa = 1.f, bb = 0.f;
#pragma unroll
  for (int i = 0; i < 32; i += 2) {
    int byo = (2 * (t0 + i)) ^ sw;
    unsigned int zu = *(const unsigned int*)(zB + byo);
    unsigned int fu = *(const unsigned int*)(fB + byo);
    float z0 = h2f((unsigned short)zu), z1 = h2f((unsigned short)(zu >> 16));
    float f0 = h2f((unsigned short)fu), f1 = h2f((unsigned short)(fu >> 16));
    bb = f0 * bb + (1.f - f0) * z0;
    bb = f1 * bb + (1.f - f1) * z1;
    aa *= f0 * f1;
  }
  float2* ab = (float2*)(smem + 98304);  // [128][4] — overlays ring buf 3 (done)
  ab[h * 4 + sub] = float2{aa, bb};

  __syncthreads();

  float c = 0.f, ap = 1.f;
#pragma unroll
  for (int s = 0; s < 3; ++s)
    if (s < sub) {
      float2 v = ab[h * 4 + s];
      c = v.x * c + v.y;
      ap *= v.x;
    }

  unsigned int* pqp = pq + (m0 + t0) * (size_t)pqC + chbase + h;
#pragma unroll
  for (int i = 0; i < 32; i += 2) {
    int byo = (2 * (t0 + i)) ^ sw;
    unsigned int zu = *(const unsigned int*)(zB + byo);
    unsigned int fu = *(const unsigned int*)(fB + byo);
    unsigned int ou = *(const unsigned int*)(oB + byo);
    float z0 = h2f((unsigned short)zu), z1 = h2f((unsigned short)(zu >> 16));
    float f0 = h2f((unsigned short)fu), f1 = h2f((unsigned short)(fu >> 16));
    float o0 = h2f((unsigned short)ou), o1 = h2f((unsigned short)(ou >> 16));
    c = f0 * c + (1.f - f0) * z0; ap *= f0;
    pqp[0] = packh2(o0 * c, o0 * ap);
    c = f1 * c + (1.f - f1) * z1; ap *= f1;
    pqp[pqC] = packh2(o1 * c, o1 * ap);
    pqp += 2 * (size_t)pqC;
  }

  if (sub == 3) {
    int b = (int)(m0 >> 11);
    int chunk = ((int)m0 & 2047) >> 7;
    carry[(size_t)(b * 16 + chunk) * C + chbase + h] = float2{ap, c};
  }
}

// ---------- sequential chunk combine (16 steps, tiny) ----------
__global__ void scan_combine_kernel(const float2* __restrict__ carry,
                                    float* __restrict__ cin, int C) {
  int gid = blockIdx.x * 256 + threadIdx.x;  // 32*C
  int b = gid / C, q = gid - b * C;
  float c = 0.f;
#pragma unroll
  for (int ch = 0; ch < 16; ++ch) {
    size_t idx = (size_t)(b * 16 + ch) * C + q;
    cin[idx] = c;
    float2 ab = carry[idx];
    c = ab.x * c + ab.y;
  }
}

// ---------- elementwise final: out = p + q * cin ----------
__global__ void final_kernel(const unsigned int* __restrict__ pq,
                             const float* __restrict__ cin,
                             float* __restrict__ out,
                             int c4shift, int C, int outbase, int niter) {
  for (int it = 0; it < niter; ++it) {
    int idx = (blockIdx.x * 256 + threadIdx.x) + it * 2097152;
    int m = idx >> c4shift;
    int c4 = idx & ((1 << c4shift) - 1);
    uint4 v = ((const uint4*)pq)[(size_t)idx];
    int b = m >> 11, chunk = (m >> 7) & 15;
    float4 cv = *(const float4*)(cin + (size_t)(b * 16 + chunk) * C + c4 * 4);
    float4 r;
    r.x = h2f((unsigned short)v.x) + h2f((unsigned short)(v.x >> 16)) * cv.x;
    r.y = h2f((unsigned short)v.y) + h2f((unsigned short)(v.y >> 16)) * cv.y;
    r.z = h2f((unsigned short)v.z) + h2f((unsigned short)(v.z >> 16)) * cv.z;
    r.w = h2f((unsigned short)v.w) + h2f((unsigned short)(v.w >> 16)) * cv.w;
    *(float4*)(out + (size_t)m * 1024 + outbase + c4 * 4) = r;
  }
}

// ---------- round-1 fused fallback (tiny-ws path; old W layout) ----------
#define NB 192
#define BT 64
__global__ __launch_bounds__(256, 2)
void qrnn_kernel(const float* __restrict__ x,
                 const float* __restrict__ bf_, const float* __restrict__ bb_,
                 const unsigned short* __restrict__ wt,
                 float* __restrict__ out) {
  __shared__ __align__(16) unsigned short sA[64 * 64];
  __shared__ float sG[64 * 193];
  __shared__ float sBias[NB];
  const int tid  = threadIdx.x;
  const int lane = tid & 63;
  const int wv   = tid >> 6;
  int p = blockIdx.x;
  int xcd = p & 7, slot = p >> 3;
  int b   = xcd * 4 + (slot >> 4);
  int v   = slot & 15;
  int dir = v >> 3, ht = v & 7;
  int h0  = ht * 64;
  if (tid < NB) {
    const float* bsrc = dir ? bb_ : bf_;
    sBias[tid] = bsrc[((tid >> 6) << 9) + h0 + (tid & 63)];
  }
  const float* xb = x + (size_t)b * TT * DD;
  const unsigned short* wtd = wt + (size_t)dir * 1536 * 512;
  size_t brow[3];
#pragma unroll
  for (int j = 0; j < 3; j++) {
    int n = 48 * wv + 16 * j + (lane & 15);
    brow[j] = (size_t)(((n >> 6) << 9) + h0 + (n & 63)) * 512 + 8 * (lane >> 4);
  }
  int a_off[2][4];
#pragma unroll
  for (int kk = 0; kk < 2; kk++)
#pragma unroll
    for (int m = 0; m < 4; m++) {
      int row = 16 * m + (lane & 15);
      a_off[kk][m] = row * 128 + ((64 * kk + 16 * (lane >> 4)) ^ ((row & 7) << 4));
    }
  int s_trow[4], s_kq[4], s_woff[4];
#pragma unroll
  for (int i = 0; i < 4; i++) {
    int q = tid + 256 * i;
    s_trow[i] = q >> 4;
    s_kq[i]   = q & 15;
    s_woff[i] = s_trow[i] * 128 + ((8 * s_kq[i]) ^ ((s_trow[i] & 7) << 4));
  }
  float c = 0.f;
  f32x4 acc[4][3];
  for (int t0 = 0; t0 < TT; t0 += BT) {
#pragma unroll
    for (int m = 0; m < 4; m++)
#pragma unroll
      for (int j = 0; j < 3; j++)
        acc[m][j] = f32x4{0.f, 0.f, 0.f, 0.f};
    float4 vv[4];
#pragma unroll
    for (int i = 0; i < 4; i++)
      vv[i] = *(const float4*)(xb + (size_t)(t0 + s_trow[i]) * DD + 4 * s_kq[i]);
#pragma unroll
    for (int ks = 0; ks < 8; ks++) {
      __syncthreads();
#pragma unroll
      for (int i = 0; i < 4; i++) {
        ushort4 u;
        u.x = f2bf(vv[i].x); u.y = f2bf(vv[i].y);
        u.z = f2bf(vv[i].z); u.w = f2bf(vv[i].w);
        *(ushort4*)((char*)sA + s_woff[i]) = u;
      }
      if (ks < 7) {
        int k0n = (ks + 1) * 64;
#pragma unroll
        for (int i = 0; i < 4; i++)
          vv[i] = *(const float4*)(xb + (size_t)(t0 + s_trow[i]) * DD + k0n + 4 * s_kq[i]);
      }
      __syncthreads();
      const char* sAb = (const char*)sA;
      int k0 = ks * 64;
#pragma unroll
      for (int kk = 0; kk < 2; kk++) {
        short8 bfr[3];
#pragma unroll
        for (int j = 0; j < 3; j++)
          bfr[j] = *(const short8*)(wtd + brow[j] + k0 + 32 * kk);
#pragma unroll
        for (int m = 0; m < 4; m++) {
          short8 afr = *(const short8*)(sAb + a_off[kk][m]);
#pragma unroll
          for (int j = 0; j < 3; j++)
            acc[m][j] = __builtin_amdgcn_mfma_f32_16x16x32_bf16(afr, bfr[j], acc[m][j], 0, 0, 0);
        }
      }
    }
#pragma unroll
    for (int m = 0; m < 4; m++)
#pragma unroll
      for (int j = 0; j < 3; j++) {
        int col   = 48 * wv + 16 * j + (lane & 15);
        int rbase = 16 * m + 4 * (lane >> 4);
#pragma unroll
        for (int r = 0; r < 4; r++)
          sG[(rbase + r) * 193 + col] = acc[m][j][r];
      }
    __syncthreads();
    for (int idx = tid; idx < 64 * NB; idx += 256) {
      int t = idx / NB;
      int n = idx - t * NB;
      float g = sG[t * 193 + n] + sBias[n];
      float res;
      if (n < 64) { float e = __expf(2.f * g); res = 1.f - 2.f / (e + 1.f); }
      else        { res = 1.f / (1.f + __expf(-g)); }
      sG[t * 193 + n] = res;
    }
    __syncthreads();
    if (tid < 64) {
      float* og = out + ((size_t)(b * TT + t0)) * 1024 + (dir << 9) + h0 + tid;
      float cc = c;
#pragma unroll 8
      for (int t = 0; t < BT; t++) {
        float z = sG[t * 193 + tid];
        float f = sG[t * 193 + 64 + tid];
        float o = sG[t * 193 + 128 + tid];
        cc = z + f * (cc - z);
        og[(size_t)t << 10] = o * cc;
      }
      c = cc;
    }
  }
}

extern "C" void kernel_launch(void* const* d_in, const int* in_sizes, int n_in,
                              void* d_out, int out_size, void* d_ws, size_t ws_size,
                              hipStream_t stream) {
  const float* x   = (const float*)d_in[0];
  const float* W_f = (const float*)d_in[1];
  const float* b_f = (const float*)d_in[2];
  const float* W_b = (const float*)d_in[3];
  const float* b_b = (const float*)d_in[4];
  float* out = (float*)d_out;

  char* ws = (char*)d_ws;
  const size_t OFF_WT    = 0;                    // 3 MiB
  const size_t OFF_CB    = 3145728;              // 12 KiB
  const size_t OFF_CARRY = 3158016;              // <=4 MiB
  const size_t OFF_CIN   = 7352320;              // <=2 MiB
  const size_t OFF_XBF   = 9449472;              // 64 MiB
  const size_t OFF_PQ    = 76558336;
  const size_t NEED_FULL = OFF_PQ + 268435456ull; // 345.0 MB
  const size_t NEED_DIR  = OFF_PQ + 134217728ull; // 210.8 MB

  unsigned short* wt   = (unsigned short*)(ws + OFF_WT);
  float* cbias         = (float*)(ws + OFF_CB);
  float2* carry        = (float2*)(ws + OFF_CARRY);
  float* cin           = (float*)(ws + OFF_CIN);
  unsigned short* xbf  = (unsigned short*)(ws + OFF_XBF);
  unsigned int* pq     = (unsigned int*)(ws + OFF_PQ);

  if (ws_size >= NEED_FULL) {
    xconv_kernel<<<16384, 256, 0, stream>>>(x, xbf);
    wtrans_new_kernel<<<1536, 256, 0, stream>>>(W_f, W_b, wt);
    cbias_kernel<<<12, 256, 0, stream>>>(b_f, b_b, cbias);
    gemm_scan_kernel<<<4096, 512, 0, stream>>>(xbf, wt, cbias, pq, carry, 8, 1024, 1024);
    scan_combine_kernel<<<128, 256, 0, stream>>>(carry, cin, 1024);
    final_kernel<<<8192, 256, 0, stream>>>(pq, cin, out, 8, 1024, 0, 8);
  } else if (ws_size >= NEED_DIR) {
    xconv_kernel<<<16384, 256, 0, stream>>>(x, xbf);
    wtrans_new_kernel<<<1536, 256, 0, stream>>>(W_f, W_b, wt);
    cbias_kernel<<<12, 256, 0, stream>>>(b_f, b_b, cbias);
    for (int dir = 0; dir < 2; ++dir) {
      gemm_scan_kernel<<<2048, 512, 0, stream>>>(xbf, wt + (size_t)dir * 1536 * 512,
                                                 cbias + dir * 1536, pq, carry, 4, 512, 512);
      scan_combine_kernel<<<64, 256, 0, stream>>>(carry, cin, 512);
      final_kernel<<<8192, 256, 0, stream>>>(pq, cin, out, 7, 512, dir * 512, 4);
    }
  } else {
    wtrans_old_kernel<<<1536, 256, 0, stream>>>(W_f, W_b, wt);
    qrnn_kernel<<<512, 256, 0, stream>>>(x, b_f, b_b, wt, out);
  }
}

// Round 5
// 457.430 us; speedup vs baseline: 1.2094x; 1.1893x over previous
//
#include <hip/hip_runtime.h>
#include <hip/hip_fp16.h>

typedef __attribute__((ext_vector_type(8))) short short8;
typedef __attribute__((ext_vector_type(4))) float f32x4;

#define TT 2048
#define DD 512

__device__ __forceinline__ unsigned short f2bf(float f) {
  unsigned int u = __float_as_uint(f);
  u += 0x7FFFu + ((u >> 16) & 1u);
  return (unsigned short)(u >> 16);
}
__device__ __forceinline__ unsigned short f2h(float f) {
  return __half_as_ushort(__float2half(f));
}
__device__ __forceinline__ float h2f(unsigned short u) {
  return __half2float(__ushort_as_half(u));
}
__device__ __forceinline__ unsigned int packh2(float a, float b) {
  return (unsigned int)f2h(a) | ((unsigned int)f2h(b) << 16);
}
__device__ __forceinline__ void gload16(const void* g, void* l) {
  __builtin_amdgcn_global_load_lds((const __attribute__((address_space(1))) void*)g,
                                   (__attribute__((address_space(3))) void*)l, 16, 0, 0);
}

// ---------- prep kernels ----------

__global__ void xconv_kernel(const float* __restrict__ x, unsigned short* __restrict__ xbf) {
  int i = blockIdx.x * 256 + threadIdx.x;
  const float4* p = (const float4*)x + (size_t)i * 2;
  float4 a = p[0], b = p[1];
  short8 o;
  o[0] = f2bf(a.x); o[1] = f2bf(a.y); o[2] = f2bf(a.z); o[3] = f2bf(a.w);
  o[4] = f2bf(b.x); o[5] = f2bf(b.y); o[6] = f2bf(b.z); o[7] = f2bf(b.w);
  *((short8*)xbf + i) = o;
}

// W[512][1536] fp32 -> Wt[dir][n'][512 k] bf16, n' = (h>>6)*192 + gate*64 + (h&63)
__global__ void wtrans_new_kernel(const float* __restrict__ Wf,
                                  const float* __restrict__ Wb,
                                  unsigned short* __restrict__ wt) {
  __shared__ float tile[32][33];
  int bid = blockIdx.x;            // 2 * 16 * 48
  int d   = bid / 768;
  int rem = bid - d * 768;
  int kt = rem & 15;
  int ct = rem >> 4;
  const float* W = d ? Wb : Wf;
  int k0 = kt * 32, c0 = ct * 32;
  int r = threadIdx.x >> 5, c = threadIdx.x & 31;
#pragma unroll
  for (int i = 0; i < 4; i++)
    tile[r + 8*i][c] = W[(size_t)(k0 + r + 8*i) * 1536 + c0 + c];
  __syncthreads();
#pragma unroll
  for (int i = 0; i < 4; i++) {
    int col = c0 + r + 8*i;
    int gate = col >> 9, hh = col & 511;
    int nn = (hh >> 6) * 192 + gate * 64 + (hh & 63);
    wt[((size_t)d * 1536 + nn) * 512 + k0 + c] = f2bf(tile[c][r + 8*i]);
  }
}

// old layout for fallback kernel
__global__ void wtrans_old_kernel(const float* __restrict__ Wf,
                                  const float* __restrict__ Wb,
                                  unsigned short* __restrict__ wt) {
  __shared__ float tile[32][33];
  int bid = blockIdx.x;
  int d   = bid / 768;
  int rem = bid - d * 768;
  int kt = rem & 15;
  int ct = rem >> 4;
  const float* W = d ? Wb : Wf;
  int k0 = kt * 32, c0 = ct * 32;
  int r = threadIdx.x >> 5, c = threadIdx.x & 31;
#pragma unroll
  for (int i = 0; i < 4; i++)
    tile[r + 8*i][c] = W[(size_t)(k0 + r + 8*i) * 1536 + c0 + c];
  __syncthreads();
  unsigned short* outp = wt + ((size_t)d * 1536 + c0) * 512 + k0;
#pragma unroll
  for (int i = 0; i < 4; i++)
    outp[(size_t)(r + 8*i) * 512 + c] = f2bf(tile[c][r + 8*i]);
}

__global__ void cbias_kernel(const float* __restrict__ bf_, const float* __restrict__ bb_,
                             float* __restrict__ cb) {
  int t = blockIdx.x * 256 + threadIdx.x;   // 3072
  int d = t / 1536, cc = t - d * 1536;
  int gate = cc >> 9, hh = cc & 511;
  int nn = (hh >> 6) * 192 + gate * 64 + (hh & 63);
  cb[d * 1536 + nn] = (d ? bb_ : bf_)[cc];
}

// ---------- fused GEMM + activation + in-block fo-pool scan ----------
// Tile 128(t) x 192(3 gates x 64 h), BK=64, round-2 core shape: single 40KB buffer,
// gload16 staging, 2 barriers/K-tile, (row&7)<<4 swizzle. 4 waves of 32t x 192n.
// Epilogue: act -> fp16 gates LDS [h][t-pair] with (h<<2) XOR (bank = t2^h, conflict-free)
// -> 2-level scan over 128 t -> store pq u32 + per-chunk carry.
__global__ __launch_bounds__(256, 3)
void gemm_scan2_kernel(const unsigned short* __restrict__ xbf,
                       const unsigned short* __restrict__ wt,
                       const float* __restrict__ cb,
                       unsigned int* __restrict__ pq,
                       float2* __restrict__ carry,
                       int nshift, int pqC, int C) {
  __shared__ __align__(16) char smem[51200];  // A 16K | B 24K ; overlay gates 48K | ab 2K

  int bid = blockIdx.x;
  int cpx = gridDim.x >> 3;
  int bid2 = (bid & 7) * cpx + (bid >> 3);
  int bn = bid2 & ((1 << nshift) - 1);
  int bm = bid2 >> nshift;
  size_t m0 = (size_t)bm * 128;
  int dir = bn >> 3, hb = bn & 7;
  int nbase = dir * 1536 + hb * 192;     // wt row base
  int chbase = dir * 512 + hb * 64;      // pq channel base

  int tid = threadIdx.x, lane = tid & 63, wv = tid >> 6;

  // staging source pointers (linear LDS dest, inverse-swizzled source)
  const char* aS[4];
  const char* bS[6];
#pragma unroll
  for (int i = 0; i < 4; ++i) {
    int l = tid + 256 * i, row = l >> 3;
    int koff = ((l & 7) * 16) ^ ((row & 7) << 4);
    aS[i] = (const char*)xbf + (m0 + row) * 1024 + koff;
  }
#pragma unroll
  for (int i = 0; i < 6; ++i) {
    int l = tid + 256 * i, row = l >> 3;
    int koff = ((l & 7) * 16) ^ ((row & 7) << 4);
    bS[i] = (const char*)wt + (size_t)(nbase + row) * 1024 + koff;
  }

  // fragment LDS offsets (ks=0; ks=1 addr = offset ^ 64)
  int aoff[2];
#pragma unroll
  for (int mf = 0; mf < 2; ++mf) {
    int row = wv * 32 + mf * 16 + (lane & 15);
    aoff[mf] = row * 128 + (((lane >> 4) * 16) ^ ((row & 7) << 4));
  }
  int boff[12];
#pragma unroll
  for (int j = 0; j < 12; ++j) {
    int row = j * 16 + (lane & 15);
    boff[j] = 16384 + row * 128 + (((lane >> 4) * 16) ^ ((row & 7) << 4));
  }

  f32x4 acc[2][12];
#pragma unroll
  for (int mf = 0; mf < 2; ++mf)
#pragma unroll
    for (int j = 0; j < 12; ++j)
      acc[mf][j] = f32x4{0.f, 0.f, 0.f, 0.f};

  for (int kt = 0; kt < 8; ++kt) {
    if (kt) __syncthreads();
    int kb = kt * 128;
#pragma unroll
    for (int i = 0; i < 4; ++i)
      gload16(aS[i] + kb, smem + tid * 16 + i * 4096);
#pragma unroll
    for (int i = 0; i < 6; ++i)
      gload16(bS[i] + kb, smem + 16384 + tid * 16 + i * 4096);
    __syncthreads();
#pragma unroll
    for (int ks = 0; ks < 2; ++ks) {
      int kx = ks * 64;
      short8 a0 = *(const short8*)(smem + (aoff[0] ^ kx));
      short8 a1 = *(const short8*)(smem + (aoff[1] ^ kx));
#pragma unroll
      for (int g = 0; g < 3; ++g) {
        short8 b0 = *(const short8*)(smem + (boff[4*g+0] ^ kx));
        short8 b1 = *(const short8*)(smem + (boff[4*g+1] ^ kx));
        short8 b2 = *(const short8*)(smem + (boff[4*g+2] ^ kx));
        short8 b3 = *(const short8*)(smem + (boff[4*g+3] ^ kx));
        acc[0][4*g+0] = __builtin_amdgcn_mfma_f32_16x16x32_bf16(a0, b0, acc[0][4*g+0], 0, 0, 0);
        acc[1][4*g+0] = __builtin_amdgcn_mfma_f32_16x16x32_bf16(a1, b0, acc[1][4*g+0], 0, 0, 0);
        acc[0][4*g+1] = __builtin_amdgcn_mfma_f32_16x16x32_bf16(a0, b1, acc[0][4*g+1], 0, 0, 0);
        acc[1][4*g+1] = __builtin_amdgcn_mfma_f32_16x16x32_bf16(a1, b1, acc[1][4*g+1], 0, 0, 0);
        acc[0][4*g+2] = __builtin_amdgcn_mfma_f32_16x16x32_bf16(a0, b2, acc[0][4*g+2], 0, 0, 0);
        acc[1][4*g+2] = __builtin_amdgcn_mfma_f32_16x16x32_bf16(a1, b2, acc[1][4*g+2], 0, 0, 0);
        acc[0][4*g+3] = __builtin_amdgcn_mfma_f32_16x16x32_bf16(a0, b3, acc[0][4*g+3], 0, 0, 0);
        acc[1][4*g+3] = __builtin_amdgcn_mfma_f32_16x16x32_bf16(a1, b3, acc[1][4*g+3], 0, 0, 0);
      }
    }
  }

  // bias
  float cbv[12];
#pragma unroll
  for (int j = 0; j < 12; ++j)
    cbv[j] = cb[nbase + j * 16 + (lane & 15)];

  __syncthreads();   // compute done; overlay gates onto staging LDS

  // gates -> LDS fp16 [gate][h=64 rows of 256B][t-pair u32], byte = (2*t) ^ (h<<2)
#pragma unroll
  for (int mf = 0; mf < 2; ++mf) {
    int base_t = wv * 32 + mf * 16 + (lane >> 4) * 4;
#pragma unroll
    for (int j = 0; j < 12; ++j) {
      int g = j >> 2;
      int hsub = (j & 3) * 16 + (lane & 15);
      float v[4], a[4];
#pragma unroll
      for (int r = 0; r < 4; ++r) v[r] = acc[mf][j][r] + cbv[j];
      if (g == 0) {
#pragma unroll
        for (int r = 0; r < 4; ++r) { float e = __expf(2.f * v[r]); a[r] = 1.f - 2.f / (e + 1.f); }
      } else {
#pragma unroll
        for (int r = 0; r < 4; ++r) a[r] = 1.f / (1.f + __expf(-v[r]));
      }
      char* gp = smem + g * 16384 + hsub * 256;
      int sx = hsub << 2;
      *(unsigned int*)(gp + ((2 * base_t) ^ sx))     = packh2(a[0], a[1]);
      *(unsigned int*)(gp + ((2 * base_t + 4) ^ sx)) = packh2(a[2], a[3]);
    }
  }

  __syncthreads();

  // two-level scan: thread (h = tid&63, sub = tid>>6) owns t in [sub*32, sub*32+32)
  int h = tid & 63, sub = tid >> 6;
  const char* zB = smem + h * 256;
  const char* fB = smem + 16384 + h * 256;
  const char* oB = smem + 32768 + h * 256;
  int sx = h << 2;

  float A = 1.f, Bv = 0.f;
#pragma unroll
  for (int i = 0; i < 16; ++i) {
    int byo = (sub * 64 + 4 * i) ^ sx;
    unsigned int zz = *(const unsigned int*)(zB + byo);
    unsigned int ff = *(const unsigned int*)(fB + byo);
    float z0 = h2f((unsigned short)zz), z1 = h2f((unsigned short)(zz >> 16));
    float f0 = h2f((unsigned short)ff), f1 = h2f((unsigned short)(ff >> 16));
    Bv = f0 * Bv + (1.f - f0) * z0;
    Bv = f1 * Bv + (1.f - f1) * z1;
    A *= f0 * f1;
  }
  float2* ab = (float2*)(smem + 49152);   // [64][4]
  ab[h * 4 + sub] = float2{A, Bv};

  __syncthreads();

  float c = 0.f, ap = 1.f;
#pragma unroll
  for (int s = 0; s < 3; ++s)
    if (s < sub) {
      float2 v = ab[h * 4 + s];
      c = v.x * c + v.y;
      ap *= v.x;
    }

  unsigned int* pqp = pq + (m0 + sub * 32) * (size_t)pqC + chbase + h;
#pragma unroll
  for (int i = 0; i < 16; ++i) {
    int byo = (sub * 64 + 4 * i) ^ sx;
    unsigned int zz = *(const unsigned int*)(zB + byo);
    unsigned int ff = *(const unsigned int*)(fB + byo);
    unsigned int oo = *(const unsigned int*)(oB + byo);
    float z0 = h2f((unsigned short)zz), z1 = h2f((unsigned short)(zz >> 16));
    float f0 = h2f((unsigned short)ff), f1 = h2f((unsigned short)(ff >> 16));
    float o0 = h2f((unsigned short)oo), o1 = h2f((unsigned short)(oo >> 16));
    c = f0 * c + (1.f - f0) * z0; ap *= f0;
    pqp[0] = packh2(o0 * c, o0 * ap);
    c = f1 * c + (1.f - f1) * z1; ap *= f1;
    pqp[pqC] = packh2(o1 * c, o1 * ap);
    pqp += 2 * (size_t)pqC;
  }

  if (sub == 3) {
    int b = (int)(m0 >> 11);
    int chunk = ((int)m0 & 2047) >> 7;
    carry[(size_t)(b * 16 + chunk) * C + chbase + h] = float2{ap, c};
  }
}

// ---------- sequential chunk combine (16 steps, tiny) ----------
__global__ void scan_combine_kernel(const float2* __restrict__ carry,
                                    float* __restrict__ cin, int C) {
  int gid = blockIdx.x * 256 + threadIdx.x;  // 32*C
  int b = gid / C, q = gid - b * C;
  float c = 0.f;
#pragma unroll
  for (int ch = 0; ch < 16; ++ch) {
    size_t idx = (size_t)(b * 16 + ch) * C + q;
    cin[idx] = c;
    float2 ab = carry[idx];
    c = ab.x * c + ab.y;
  }
}

// ---------- elementwise final: out = p + q * cin ----------
__global__ void final_kernel(const unsigned int* __restrict__ pq,
                             const float* __restrict__ cin,
                             float* __restrict__ out,
                             int c4shift, int C, int outbase, int niter) {
  for (int it = 0; it < niter; ++it) {
    int idx = (blockIdx.x * 256 + threadIdx.x) + it * 2097152;
    int m = idx >> c4shift;
    int c4 = idx & ((1 << c4shift) - 1);
    uint4 v = ((const uint4*)pq)[(size_t)idx];
    int b = m >> 11, chunk = (m >> 7) & 15;
    float4 cv = *(const float4*)(cin + (size_t)(b * 16 + chunk) * C + c4 * 4);
    float4 r;
    r.x = h2f((unsigned short)v.x) + h2f((unsigned short)(v.x >> 16)) * cv.x;
    r.y = h2f((unsigned short)v.y) + h2f((unsigned short)(v.y >> 16)) * cv.y;
    r.z = h2f((unsigned short)v.z) + h2f((unsigned short)(v.z >> 16)) * cv.z;
    r.w = h2f((unsigned short)v.w) + h2f((unsigned short)(v.w >> 16)) * cv.w;
    *(float4*)(out + (size_t)m * 1024 + outbase + c4 * 4) = r;
  }
}

// ---------- round-1 fused fallback (tiny-ws path; old W layout) ----------
#define NB 192
#define BT 64
__global__ __launch_bounds__(256, 2)
void qrnn_kernel(const float* __restrict__ x,
                 const float* __restrict__ bf_, const float* __restrict__ bb_,
                 const unsigned short* __restrict__ wt,
                 float* __restrict__ out) {
  __shared__ __align__(16) unsigned short sA[64 * 64];
  __shared__ float sG[64 * 193];
  __shared__ float sBias[NB];
  const int tid  = threadIdx.x;
  const int lane = tid & 63;
  const int wv   = tid >> 6;
  int p = blockIdx.x;
  int xcd = p & 7, slot = p >> 3;
  int b   = xcd * 4 + (slot >> 4);
  int v   = slot & 15;
  int dir = v >> 3, ht = v & 7;
  int h0  = ht * 64;
  if (tid < NB) {
    const float* bsrc = dir ? bb_ : bf_;
    sBias[tid] = bsrc[((tid >> 6) << 9) + h0 + (tid & 63)];
  }
  const float* xb = x + (size_t)b * TT * DD;
  const unsigned short* wtd = wt + (size_t)dir * 1536 * 512;
  size_t brow[3];
#pragma unroll
  for (int j = 0; j < 3; j++) {
    int n = 48 * wv + 16 * j + (lane & 15);
    brow[j] = (size_t)(((n >> 6) << 9) + h0 + (n & 63)) * 512 + 8 * (lane >> 4);
  }
  int a_off[2][4];
#pragma unroll
  for (int kk = 0; kk < 2; kk++)
#pragma unroll
    for (int m = 0; m < 4; m++) {
      int row = 16 * m + (lane & 15);
      a_off[kk][m] = row * 128 + ((64 * kk + 16 * (lane >> 4)) ^ ((row & 7) << 4));
    }
  int s_trow[4], s_kq[4], s_woff[4];
#pragma unroll
  for (int i = 0; i < 4; i++) {
    int q = tid + 256 * i;
    s_trow[i] = q >> 4;
    s_kq[i]   = q & 15;
    s_woff[i] = s_trow[i] * 128 + ((8 * s_kq[i]) ^ ((s_trow[i] & 7) << 4));
  }
  float c = 0.f;
  f32x4 acc[4][3];
  for (int t0 = 0; t0 < TT; t0 += BT) {
#pragma unroll
    for (int m = 0; m < 4; m++)
#pragma unroll
      for (int j = 0; j < 3; j++)
        acc[m][j] = f32x4{0.f, 0.f, 0.f, 0.f};
    float4 vv[4];
#pragma unroll
    for (int i = 0; i < 4; i++)
      vv[i] = *(const float4*)(xb + (size_t)(t0 + s_trow[i]) * DD + 4 * s_kq[i]);
#pragma unroll
    for (int ks = 0; ks < 8; ks++) {
      __syncthreads();
#pragma unroll
      for (int i = 0; i < 4; i++) {
        ushort4 u;
        u.x = f2bf(vv[i].x); u.y = f2bf(vv[i].y);
        u.z = f2bf(vv[i].z); u.w = f2bf(vv[i].w);
        *(ushort4*)((char*)sA + s_woff[i]) = u;
      }
      if (ks < 7) {
        int k0n = (ks + 1) * 64;
#pragma unroll
        for (int i = 0; i < 4; i++)
          vv[i] = *(const float4*)(xb + (size_t)(t0 + s_trow[i]) * DD + k0n + 4 * s_kq[i]);
      }
      __syncthreads();
      const char* sAb = (const char*)sA;
      int k0 = ks * 64;
#pragma unroll
      for (int kk = 0; kk < 2; kk++) {
        short8 bfr[3];
#pragma unroll
        for (int j = 0; j < 3; j++)
          bfr[j] = *(const short8*)(wtd + brow[j] + k0 + 32 * kk);
#pragma unroll
        for (int m = 0; m < 4; m++) {
          short8 afr = *(const short8*)(sAb + a_off[kk][m]);
#pragma unroll
          for (int j = 0; j < 3; j++)
            acc[m][j] = __builtin_amdgcn_mfma_f32_16x16x32_bf16(afr, bfr[j], acc[m][j], 0, 0, 0);
        }
      }
    }
#pragma unroll
    for (int m = 0; m < 4; m++)
#pragma unroll
      for (int j = 0; j < 3; j++) {
        int col   = 48 * wv + 16 * j + (lane & 15);
        int rbase = 16 * m + 4 * (lane >> 4);
#pragma unroll
        for (int r = 0; r < 4; r++)
          sG[(rbase + r) * 193 + col] = acc[m][j][r];
      }
    __syncthreads();
    for (int idx = tid; idx < 64 * NB; idx += 256) {
      int t = idx / NB;
      int n = idx - t * NB;
      float g = sG[t * 193 + n] + sBias[n];
      float res;
      if (n < 64) { float e = __expf(2.f * g); res = 1.f - 2.f / (e + 1.f); }
      else        { res = 1.f / (1.f + __expf(-g)); }
      sG[t * 193 + n] = res;
    }
    __syncthreads();
    if (tid < 64) {
      float* og = out + ((size_t)(b * TT + t0)) * 1024 + (dir << 9) + h0 + tid;
      float cc = c;
#pragma unroll 8
      for (int t = 0; t < BT; t++) {
        float z = sG[t * 193 + tid];
        float f = sG[t * 193 + 64 + tid];
        float o = sG[t * 193 + 128 + tid];
        cc = z + f * (cc - z);
        og[(size_t)t << 10] = o * cc;
      }
      c = cc;
    }
  }
}

extern "C" void kernel_launch(void* const* d_in, const int* in_sizes, int n_in,
                              void* d_out, int out_size, void* d_ws, size_t ws_size,
                              hipStream_t stream) {
  const float* x   = (const float*)d_in[0];
  const float* W_f = (const float*)d_in[1];
  const float* b_f = (const float*)d_in[2];
  const float* W_b = (const float*)d_in[3];
  const float* b_b = (const float*)d_in[4];
  float* out = (float*)d_out;

  char* ws = (char*)d_ws;
  const size_t OFF_WT    = 0;                    // 3 MiB
  const size_t OFF_CB    = 3145728;              // 12 KiB
  const size_t OFF_CARRY = 3158016;              // <=4 MiB
  const size_t OFF_CIN   = 7352320;              // <=2 MiB
  const size_t OFF_XBF   = 9449472;              // 64 MiB
  const size_t OFF_PQ    = 76558336;
  const size_t NEED_FULL = OFF_PQ + 268435456ull; // 345.0 MB
  const size_t NEED_DIR  = OFF_PQ + 134217728ull; // 210.8 MB

  unsigned short* wt   = (unsigned short*)(ws + OFF_WT);
  float* cbias         = (float*)(ws + OFF_CB);
  float2* carry        = (float2*)(ws + OFF_CARRY);
  float* cin           = (float*)(ws + OFF_CIN);
  unsigned short* xbf  = (unsigned short*)(ws + OFF_XBF);
  unsigned int* pq     = (unsigned int*)(ws + OFF_PQ);

  if (ws_size >= NEED_FULL) {
    xconv_kernel<<<16384, 256, 0, stream>>>(x, xbf);
    wtrans_new_kernel<<<1536, 256, 0, stream>>>(W_f, W_b, wt);
    cbias_kernel<<<12, 256, 0, stream>>>(b_f, b_b, cbias);
    gemm_scan2_kernel<<<8192, 256, 0, stream>>>(xbf, wt, cbias, pq, carry, 4, 1024, 1024);
    scan_combine_kernel<<<128, 256, 0, stream>>>(carry, cin, 1024);
    final_kernel<<<8192, 256, 0, stream>>>(pq, cin, out, 8, 1024, 0, 8);
  } else if (ws_size >= NEED_DIR) {
    xconv_kernel<<<16384, 256, 0, stream>>>(x, xbf);
    wtrans_new_kernel<<<1536, 256, 0, stream>>>(W_f, W_b, wt);
    cbias_kernel<<<12, 256, 0, stream>>>(b_f, b_b, cbias);
    for (int dir = 0; dir < 2; ++dir) {
      gemm_scan2_kernel<<<4096, 256, 0, stream>>>(xbf, wt + (size_t)dir * 1536 * 512,
                                                  cbias + dir * 1536, pq, carry, 3, 512, 512);
      scan_combine_kernel<<<64, 256, 0, stream>>>(carry, cin, 512);
      final_kernel<<<8192, 256, 0, stream>>>(pq, cin, out, 7, 512, dir * 512, 4);
    }
  } else {
    wtrans_old_kernel<<<1536, 256, 0, stream>>>(W_f, W_b, wt);
    qrnn_kernel<<<512, 256, 0, stream>>>(x, b_f, b_b, wt, out);
  }
}